// Round 5
// baseline (86.013 us; speedup 1.0000x reference)
//
#include <hip/hip_runtime.h>
#include <hip/hip_bf16.h>

typedef unsigned short u16;
typedef __attribute__((ext_vector_type(8))) short bf16x8;
typedef __attribute__((ext_vector_type(4))) float f32x4;

#define S_LEN 2048
#define NH 16

__device__ __forceinline__ u16 f2bf(float x) {
  union { float f; unsigned u; } v; v.f = x;
  unsigned r = v.u + 0x7fffu + ((v.u >> 16) & 1u);
  return (u16)(r >> 16);
}

__device__ __forceinline__ unsigned cvtpk_bf16(float lo, float hi) {
  unsigned w;
  asm("v_cvt_pk_bf16_f32 %0, %1, %2" : "=v"(w) : "v"(lo), "v"(hi));
  return w;  // bits[15:0]=bf16(lo), bits[31:16]=bf16(hi)
}

__device__ __forceinline__ void async16(const void* g, void* l) {
  __builtin_amdgcn_global_load_lds(
      (const __attribute__((address_space(1))) unsigned int*)g,
      (__attribute__((address_space(3))) unsigned int*)l, 16, 0, 0);
}

__device__ __forceinline__ f32x4 mfma16(bf16x8 a, bf16x8 b, f32x4 c) {
  return __builtin_amdgcn_mfma_f32_16x16x32_bf16(a, b, c, 0, 0, 0);
}

// scale folded into Wq/bq: 1/sqrt(64) * log2(e) so QK^T output is the exp2 arg
#define QSCALE (0.125f * 1.44269504089f)

// ---------------------------------------------------------------------------
// K1: convert/pack (region-dispatched by blockIdx.x).
// ---------------------------------------------------------------------------
__global__ __launch_bounds__(256) void convert_kernel(
    const float* __restrict__ emb, const float* __restrict__ Wq,
    const float* __restrict__ Wk, const float* __restrict__ Wv,
    const float* __restrict__ bq, const float* __restrict__ bk,
    const float* __restrict__ bv, const float* __restrict__ Wo,
    u16* __restrict__ emb_bf, u16* __restrict__ wqkv_t,
    u16* __restrict__ wo_t, float* __restrict__ bqkv) {
  __shared__ float lds[64][65];
  const int b = blockIdx.x, tid = threadIdx.x;
  if (b < 2048) {
    int i = b * 1024 + tid * 4;
    float4 v = *(const float4*)(emb + i);
    ushort4 o = {f2bf(v.x), f2bf(v.y), f2bf(v.z), f2bf(v.w)};
    *(ushort4*)(emb_bf + i) = o;
    return;
  }
  if (b < 2816) {  // W{q,k,v} transpose: per (kind, head, k-tile)
    int tt = b - 2048;
    int kind = tt >> 8;
    int rem = tt & 255;
    int h = rem >> 4, k0 = (rem & 15) << 6;
    const float* W = (kind == 0) ? Wq : ((kind == 1) ? Wk : Wv);
    const float* src = W + ((size_t)h * 1024 + k0) * 64;
#pragma unroll
    for (int rr = 0; rr < 4; ++rr) {
      int k = rr * 16 + (tid >> 4);
      int d4 = (tid & 15) << 2;
      float4 v = *(const float4*)(src + (size_t)k * 64 + d4);
      lds[k][d4] = v.x; lds[k][d4 + 1] = v.y;
      lds[k][d4 + 2] = v.z; lds[k][d4 + 3] = v.w;
    }
    __syncthreads();
    float scale = (kind == 0) ? QSCALE : 1.f;
#pragma unroll
    for (int p = 0; p < 2; ++p) {
      int d = p * 32 + (tid >> 3);
      int kb = (tid & 7) << 3;
      bf16x8 o;
#pragma unroll
      for (int j = 0; j < 8; ++j) o[j] = (short)f2bf(lds[kb + j][d] * scale);
      *(bf16x8*)(wqkv_t + (size_t)(kind * 1024 + h * 64 + d) * 1024 + k0 + kb) = o;
    }
    return;
  }
  if (b < 3072) {  // Wo transpose
    int tt = b - 2816;
    int k0 = (tt >> 4) << 6, n0 = (tt & 15) << 6;
#pragma unroll
    for (int rr = 0; rr < 4; ++rr) {
      int k = rr * 16 + (tid >> 4);
      int n4 = (tid & 15) << 2;
      float4 v = *(const float4*)(Wo + (size_t)(k0 + k) * 1024 + n0 + n4);
      lds[k][n4] = v.x; lds[k][n4 + 1] = v.y;
      lds[k][n4 + 2] = v.z; lds[k][n4 + 3] = v.w;
    }
    __syncthreads();
#pragma unroll
    for (int p = 0; p < 2; ++p) {
      int nrel = p * 32 + (tid >> 3);
      int kb = (tid & 7) << 3;
      bf16x8 o;
#pragma unroll
      for (int j = 0; j < 8; ++j) o[j] = (short)f2bf(lds[kb + j][nrel]);
      *(bf16x8*)(wo_t + (size_t)(n0 + nrel) * 1024 + k0 + kb) = o;
    }
    return;
  }
  for (int i = tid; i < 3072; i += 256) {
    int kind = i >> 10, hd = i & 1023;
    const float* bb = (kind == 0) ? bq : ((kind == 1) ? bk : bv);
    float v = bb[hd];
    bqkv[i] = (kind == 0) ? v * QSCALE : v;
  }
}

// ---------------------------------------------------------------------------
// GEMM: C[M][N] = A[M][K] * BT[N][K]^T + bias[N]
// VT_SPLIT (GEMM1 only): blocks with n0>=2048 (V heads, BN=64 == one head)
// write their tile TRANSPOSED into vt[h][d][s] instead of into C.
// ---------------------------------------------------------------------------
template <int WM, int WN, int FM, int FN, int BK, bool OUT_BF16, bool VT_SPLIT>
__global__ __launch_bounds__(WM * WN * 64) void gemm_kernel(
    const u16* __restrict__ A, const u16* __restrict__ BT,
    const float* __restrict__ bias, void* __restrict__ Cout,
    u16* __restrict__ vt, int M, int N, int K) {
  constexpr int BM = WM * FM * 16, BN = WN * FN * 16, T = WM * WN * 64;
  constexpr int RB = BK * 2;  // bytes per LDS row
  __shared__ u16 lds[2][(BM + BN) * BK];
  const int tid = threadIdx.x;
  const int lane = tid & 63, wave = tid >> 6;
  const int wr = wave / WN, wc = wave % WN;
  const int m0 = blockIdx.x * BM, n0 = blockIdx.y * BN;
  const int r = lane & 15, g = lane >> 4;
  const f32x4 fzero = {0.f, 0.f, 0.f, 0.f};
  f32x4 acc[FM][FN];
#pragma unroll
  for (int i = 0; i < FM; ++i)
#pragma unroll
    for (int j = 0; j < FN; ++j) acc[i][j] = fzero;

  constexpr int LA = (BM * RB) / (T * 16);
  constexpr int LB = (BN * RB) / (T * 16);

  auto stage = [&](int kt, int buf) {
    int k0 = kt * BK;
#pragma unroll
    for (int i = 0; i < LA; ++i) {
      int flat = i * T * 16 + tid * 16;
      int row = flat / RB, colb = flat % RB;
      async16((const char*)A + ((size_t)(m0 + row) * K + k0) * 2 + colb,
              (char*)lds[buf] + i * T * 16 + wave * 1024);
    }
#pragma unroll
    for (int i = 0; i < LB; ++i) {
      int flat = i * T * 16 + tid * 16;
      int row = flat / RB, colb = flat % RB;
      async16((const char*)BT + ((size_t)(n0 + row) * K + k0) * 2 + colb,
              (char*)lds[buf] + BM * RB + i * T * 16 + wave * 1024);
    }
  };

  stage(0, 0);
  asm volatile("s_waitcnt vmcnt(0)" ::: "memory");
  __syncthreads();

  const int NT = K / BK;
  for (int kt = 0; kt < NT; ++kt) {
    int cur = kt & 1;
    if (kt + 1 < NT) stage(kt + 1, cur ^ 1);
    const u16* Al = lds[cur];
    const u16* Bl = Al + BM * BK;
#pragma unroll
    for (int kk = 0; kk < BK / 32; ++kk) {
      bf16x8 af[FM], bfr[FN];
#pragma unroll
      for (int i = 0; i < FM; ++i)
        af[i] = *(const bf16x8*)&Al[(wr * FM * 16 + i * 16 + r) * BK + kk * 32 + g * 8];
#pragma unroll
      for (int j = 0; j < FN; ++j)
        bfr[j] = *(const bf16x8*)&Bl[(wc * FN * 16 + j * 16 + r) * BK + kk * 32 + g * 8];
#pragma unroll
      for (int i = 0; i < FM; ++i)
#pragma unroll
        for (int j = 0; j < FN; ++j)
          acc[i][j] = mfma16(af[i], bfr[j], acc[i][j]);
    }
    asm volatile("s_waitcnt vmcnt(0)" ::: "memory");
    __syncthreads();
  }

  if constexpr (VT_SPLIT) {
    if (n0 >= 2048) {  // V head: write transposed into vt[h][d][s]
      int h = (n0 - 2048) >> 6;
#pragma unroll
      for (int i = 0; i < FM; ++i)
#pragma unroll
        for (int j = 0; j < FN; ++j) {
          int d = wc * FN * 16 + j * 16 + r;        // 0..63
          int s0 = m0 + wr * FM * 16 + i * 16 + g * 4;
          float bval = bias[n0 + (d & 63)];
          ushort4 o = {f2bf(acc[i][j][0] + bval), f2bf(acc[i][j][1] + bval),
                       f2bf(acc[i][j][2] + bval), f2bf(acc[i][j][3] + bval)};
          *(ushort4*)(vt + (size_t)h * 131072 + (size_t)d * 2048 + s0) = o;
        }
      return;
    }
  }

#pragma unroll
  for (int i = 0; i < FM; ++i)
#pragma unroll
    for (int j = 0; j < FN; ++j)
#pragma unroll
      for (int e = 0; e < 4; ++e) {
        int row = m0 + wr * FM * 16 + i * 16 + g * 4 + e;
        int col = n0 + wc * FN * 16 + j * 16 + r;
        float v = acc[i][j][e] + bias[col];
        if constexpr (OUT_BF16)
          ((u16*)Cout)[(size_t)row * N + col] = f2bf(v);
        else
          ((float*)Cout)[(size_t)row * N + col] = v;
      }
}

// ---------------------------------------------------------------------------
// K4: flash attention, no-max softmax, swapped QK^T (S^T = K·Q^T).
// Block = (64 q-rows, head): 4 waves = 2 q-groups(32 rows) x 2 kv-split.
// Each wave: 32 q-rows (2 q-subtiles) -> K/V fragment reads amortized 2x.
// Per step: 128 keys staged double-buffered; P through per-wave LDS (4KB).
// ---------------------------------------------------------------------------
__global__ __launch_bounds__(256) void attn_kernel(const u16* __restrict__ qkv,
                                                   const u16* __restrict__ vt,
                                                   u16* __restrict__ concat) {
  // LDS: K dbuf [2][128][64]u16 @0 (32KB), V dbuf @32768 (32KB), P [4][4KB] @65536
  __shared__ __align__(16) char smem[81920];
  const int tid = threadIdx.x;
  const int lane = tid & 63, wave = tid >> 6;
  const int qg = wave >> 1, kvw = wave & 1;
  const int h = blockIdx.y;
  const int q0w = blockIdx.x * 64 + qg * 32;   // wave's 32 q-rows
  const int r = lane & 15, g = lane >> 4;
  const f32x4 fzero = {0.f, 0.f, 0.f, 0.f};
  char* Pw = smem + 65536 + wave * 4096;

  bf16x8 aq[2][2];  // [qi][kk]: Q[q0w+qi*16+r][kk*32+g*8..] as B-fragment
#pragma unroll
  for (int qi = 0; qi < 2; ++qi)
#pragma unroll
    for (int kk = 0; kk < 2; ++kk)
      aq[qi][kk] = *(const bf16x8*)&qkv[(size_t)(q0w + qi * 16 + r) * 3072 +
                                        h * 64 + kk * 32 + g * 8];

  f32x4 acc[4][2];  // [d-tile nt][qi]
#pragma unroll
  for (int nt = 0; nt < 4; ++nt)
#pragma unroll
    for (int qi = 0; qi < 2; ++qi) acc[nt][qi] = fzero;
  float rs[2] = {0.f, 0.f};  // per-lane partial denom, q = qi*16 + r

  auto stage = [&](int step) {
    int par = step & 1;
    int t0 = step * 128;
#pragma unroll
    for (int i = 0; i < 4; ++i) {
      int flat = i * 4096 + tid * 16;
      int row = flat >> 7;  // 0..127
      int blk = ((flat >> 4) & 7) ^ (row & 7);
      const char* srcK = (const char*)qkv +
                         ((size_t)(t0 + row) * 3072 + 1024 + h * 64) * 2 + blk * 16;
      async16(srcK, smem + par * 16384 + i * 4096 + wave * 1024);
      int c = row >> 6, d = row & 63;
      const char* srcV = (const char*)vt +
                         ((size_t)h * 131072 + (size_t)d * 2048 + t0 + c * 64) * 2 + blk * 16;
      async16(srcV, smem + 32768 + par * 16384 + i * 4096 + wave * 1024);
    }
  };

  stage(0);
  asm volatile("s_waitcnt vmcnt(0)" ::: "memory");
  __syncthreads();

  for (int step = 0; step < 16; ++step) {
    if (step + 1 < 16) stage(step + 1);
    const int par = step & 1;
    const char* Kb = smem + par * 16384 + kvw * 8192;
    const char* Vb = smem + 32768 + par * 16384 + kvw * 8192;

    // S^T = K Q^T : sv[nt][qi][e] = S[q=qi*16+r][t = nt*16 + g*4 + e]
    f32x4 sv[4][2];
    __builtin_amdgcn_s_setprio(1);
#pragma unroll
    for (int nt = 0; nt < 4; ++nt) {
      sv[nt][0] = fzero;
      sv[nt][1] = fzero;
#pragma unroll
      for (int kk = 0; kk < 2; ++kk) {
        int row = nt * 16 + r;  // K row as A-fragment
        const bf16x8 bk = *(const bf16x8*)(Kb + row * 128 +
                                           ((((kk << 2) | g) ^ (row & 7)) << 4));
        sv[nt][0] = mfma16(bk, aq[0][kk], sv[nt][0]);
        sv[nt][1] = mfma16(bk, aq[1][kk], sv[nt][1]);
      }
    }
    __builtin_amdgcn_s_setprio(0);

    // p = exp2(s'), pack bf16 pairs, store rows q=qi*16+r
#pragma unroll
    for (int nt = 0; nt < 4; ++nt)
#pragma unroll
      for (int qi = 0; qi < 2; ++qi) {
        float p0 = exp2f(sv[nt][qi][0]), p1 = exp2f(sv[nt][qi][1]);
        float p2 = exp2f(sv[nt][qi][2]), p3 = exp2f(sv[nt][qi][3]);
        rs[qi] += (p0 + p1) + (p2 + p3);
        uint2 w = {cvtpk_bf16(p0, p1), cvtpk_bf16(p2, p3)};
        int q = qi * 16 + r;
        int off = (q * 128 + nt * 32 + g * 8) ^ ((q & 7) << 4);
        *(uint2*)(Pw + off) = w;
      }

    asm volatile("s_waitcnt lgkmcnt(0)" ::: "memory");
    __builtin_amdgcn_sched_barrier(0);
    bf16x8 pa[2][2];  // [qi][tc]: A[m=q][k=t]
#pragma unroll
    for (int qi = 0; qi < 2; ++qi)
#pragma unroll
      for (int tc = 0; tc < 2; ++tc) {
        int q = qi * 16 + r;
        pa[qi][tc] = *(const bf16x8*)(Pw + ((q * 128 + tc * 64 + g * 16) ^ ((q & 7) << 4)));
      }
    __builtin_amdgcn_s_setprio(1);
#pragma unroll
    for (int nt = 0; nt < 4; ++nt)
#pragma unroll
      for (int tc = 0; tc < 2; ++tc) {
        int d = (nt << 4) | r;
        const bf16x8 bv = *(const bf16x8*)(Vb + d * 128 +
                                           ((((tc << 2) | g) ^ (d & 7)) << 4));
        acc[nt][0] = mfma16(pa[0][tc], bv, acc[nt][0]);
        acc[nt][1] = mfma16(pa[1][tc], bv, acc[nt][1]);
      }
    __builtin_amdgcn_s_setprio(0);
    asm volatile("s_waitcnt vmcnt(0)" ::: "memory");
    __syncthreads();
  }

  // full row-sums: reduce over the 4 g-groups
#pragma unroll
  for (int qi = 0; qi < 2; ++qi) {
    rs[qi] += __shfl_xor(rs[qi], 16, 64);
    rs[qi] += __shfl_xor(rs[qi], 32, 64);
  }

  // merge kv halves in LDS (aliases dead K buffers)
  float* Ox = (float*)smem;                  // [64][65]
  float* Lx = (float*)(smem + 64 * 65 * 4);  // [64]
  if (kvw == 1) {
#pragma unroll
    for (int nt = 0; nt < 4; ++nt)
#pragma unroll
      for (int qi = 0; qi < 2; ++qi)
#pragma unroll
        for (int e = 0; e < 4; ++e) {
          int qb = qg * 32 + qi * 16 + (g << 2) + e;
          Ox[qb * 65 + (nt << 4) + r] = acc[nt][qi][e];
        }
    if (g == 0) {
      Lx[qg * 32 + r] = rs[0];
      Lx[qg * 32 + 16 + r] = rs[1];
    }
  }
  __syncthreads();
  if (kvw == 0) {
#pragma unroll
    for (int qi = 0; qi < 2; ++qi) {
      float inv[4];
#pragma unroll
      for (int e = 0; e < 4; ++e) {
        float own = __shfl(rs[qi], (g << 2) | e, 64);
        inv[e] = 1.f / (own + Lx[qg * 32 + qi * 16 + (g << 2) + e]);
      }
#pragma unroll
      for (int nt = 0; nt < 4; ++nt)
#pragma unroll
        for (int e = 0; e < 4; ++e) {
          int qb = qg * 32 + qi * 16 + (g << 2) + e;
          float o = acc[nt][qi][e] + Ox[qb * 65 + (nt << 4) + r];
          concat[(size_t)(blockIdx.x * 64 + qb) * 1024 + h * 64 + (nt << 4) + r] =
              f2bf(o * inv[e]);
        }
    }
  }
}

// ---------------------------------------------------------------------------
extern "C" void kernel_launch(void* const* d_in, const int* in_sizes, int n_in,
                              void* d_out, int out_size, void* d_ws,
                              size_t ws_size, hipStream_t stream) {
  (void)in_sizes; (void)n_in; (void)out_size; (void)ws_size;
  const float* emb = (const float*)d_in[0];
  const float* Wq = (const float*)d_in[1];
  const float* bq = (const float*)d_in[2];
  const float* Wk = (const float*)d_in[3];
  const float* bk = (const float*)d_in[4];
  const float* Wv = (const float*)d_in[5];
  const float* bv = (const float*)d_in[6];
  const float* Wo = (const float*)d_in[7];
  const float* bo = (const float*)d_in[8];

  char* ws = (char*)d_ws;
  u16* emb_bf  = (u16*)(ws + 0);          // 4,194,304 B
  u16* wqkv_t  = (u16*)(ws + 4194304);    // 6,291,456 B
  u16* wo_t    = (u16*)(ws + 10485760);   // 2,097,152 B
  float* bqkv  = (float*)(ws + 12582912); // 12,288 B
  u16* qkv     = (u16*)(ws + 12595200);   // 12,582,912 B (V third unused)
  u16* vt      = (u16*)(ws + 25178112);   // 4,194,304 B
  u16* concat  = (u16*)(ws + 29372416);   // 4,194,304 B  (total ~33.6 MB)

  convert_kernel<<<3073, 256, 0, stream>>>(emb, Wq, Wk, Wv, bq, bk, bv, Wo,
                                           emb_bf, wqkv_t, wo_t, bqkv);
  gemm_kernel<2, 2, 4, 2, 64, true, true><<<dim3(16, 48), 256, 0, stream>>>(
      emb_bf, wqkv_t, bqkv, qkv, vt, 2048, 3072, 1024);
  attn_kernel<<<dim3(32, 16), 256, 0, stream>>>(qkv, vt, concat);
  gemm_kernel<2, 2, 2, 2, 64, false, false><<<dim3(32, 16), 256, 0, stream>>>(
      concat, wo_t, bo, d_out, nullptr, 2048, 1024, 1024);
}

// Round 6
// 84.612 us; speedup vs baseline: 1.0166x; 1.0166x over previous
//
#include <hip/hip_runtime.h>
#include <hip/hip_bf16.h>

typedef unsigned short u16;
typedef __attribute__((ext_vector_type(8))) short bf16x8;
typedef __attribute__((ext_vector_type(4))) float f32x4;

#define S_LEN 2048
#define NH 16

__device__ __forceinline__ u16 f2bf(float x) {
  union { float f; unsigned u; } v; v.f = x;
  unsigned r = v.u + 0x7fffu + ((v.u >> 16) & 1u);
  return (u16)(r >> 16);
}

__device__ __forceinline__ unsigned cvtpk_bf16(float lo, float hi) {
  unsigned w;
  asm("v_cvt_pk_bf16_f32 %0, %1, %2" : "=v"(w) : "v"(lo), "v"(hi));
  return w;  // bits[15:0]=bf16(lo), bits[31:16]=bf16(hi)
}

__device__ __forceinline__ void async16(const void* g, void* l) {
  __builtin_amdgcn_global_load_lds(
      (const __attribute__((address_space(1))) unsigned int*)g,
      (__attribute__((address_space(3))) unsigned int*)l, 16, 0, 0);
}

__device__ __forceinline__ f32x4 mfma16(bf16x8 a, bf16x8 b, f32x4 c) {
  return __builtin_amdgcn_mfma_f32_16x16x32_bf16(a, b, c, 0, 0, 0);
}

// scale folded into Wq/bq: 1/sqrt(64) * log2(e) so QK^T output is the exp2 arg
#define QSCALE (0.125f * 1.44269504089f)

// ---------------------------------------------------------------------------
// K1: convert/pack (region-dispatched by blockIdx.x).
// ---------------------------------------------------------------------------
__global__ __launch_bounds__(256) void convert_kernel(
    const float* __restrict__ emb, const float* __restrict__ Wq,
    const float* __restrict__ Wk, const float* __restrict__ Wv,
    const float* __restrict__ bq, const float* __restrict__ bk,
    const float* __restrict__ bv, const float* __restrict__ Wo,
    u16* __restrict__ emb_bf, u16* __restrict__ wqkv_t,
    u16* __restrict__ wo_t, float* __restrict__ bqkv) {
  __shared__ float lds[64][65];
  const int b = blockIdx.x, tid = threadIdx.x;
  if (b < 2048) {
    int i = b * 1024 + tid * 4;
    float4 v = *(const float4*)(emb + i);
    ushort4 o = {f2bf(v.x), f2bf(v.y), f2bf(v.z), f2bf(v.w)};
    *(ushort4*)(emb_bf + i) = o;
    return;
  }
  if (b < 2816) {  // W{q,k,v} transpose: per (kind, head, k-tile)
    int tt = b - 2048;
    int kind = tt >> 8;
    int rem = tt & 255;
    int h = rem >> 4, k0 = (rem & 15) << 6;
    const float* W = (kind == 0) ? Wq : ((kind == 1) ? Wk : Wv);
    const float* src = W + ((size_t)h * 1024 + k0) * 64;
#pragma unroll
    for (int rr = 0; rr < 4; ++rr) {
      int k = rr * 16 + (tid >> 4);
      int d4 = (tid & 15) << 2;
      float4 v = *(const float4*)(src + (size_t)k * 64 + d4);
      lds[k][d4] = v.x; lds[k][d4 + 1] = v.y;
      lds[k][d4 + 2] = v.z; lds[k][d4 + 3] = v.w;
    }
    __syncthreads();
    float scale = (kind == 0) ? QSCALE : 1.f;
#pragma unroll
    for (int p = 0; p < 2; ++p) {
      int d = p * 32 + (tid >> 3);
      int kb = (tid & 7) << 3;
      bf16x8 o;
#pragma unroll
      for (int j = 0; j < 8; ++j) o[j] = (short)f2bf(lds[kb + j][d] * scale);
      *(bf16x8*)(wqkv_t + (size_t)(kind * 1024 + h * 64 + d) * 1024 + k0 + kb) = o;
    }
    return;
  }
  if (b < 3072) {  // Wo transpose
    int tt = b - 2816;
    int k0 = (tt >> 4) << 6, n0 = (tt & 15) << 6;
#pragma unroll
    for (int rr = 0; rr < 4; ++rr) {
      int k = rr * 16 + (tid >> 4);
      int n4 = (tid & 15) << 2;
      float4 v = *(const float4*)(Wo + (size_t)(k0 + k) * 1024 + n0 + n4);
      lds[k][n4] = v.x; lds[k][n4 + 1] = v.y;
      lds[k][n4 + 2] = v.z; lds[k][n4 + 3] = v.w;
    }
    __syncthreads();
#pragma unroll
    for (int p = 0; p < 2; ++p) {
      int nrel = p * 32 + (tid >> 3);
      int kb = (tid & 7) << 3;
      bf16x8 o;
#pragma unroll
      for (int j = 0; j < 8; ++j) o[j] = (short)f2bf(lds[kb + j][nrel]);
      *(bf16x8*)(wo_t + (size_t)(n0 + nrel) * 1024 + k0 + kb) = o;
    }
    return;
  }
  for (int i = tid; i < 3072; i += 256) {
    int kind = i >> 10, hd = i & 1023;
    const float* bb = (kind == 0) ? bq : ((kind == 1) ? bk : bv);
    float v = bb[hd];
    bqkv[i] = (kind == 0) ? v * QSCALE : v;
  }
}

// ---------------------------------------------------------------------------
// GEMM: C[M][N] = A[M][K] * BT[N][K]^T + bias[N]
// VT_SPLIT (GEMM1 only): blocks with n0>=2048 (V heads, BN=64 == one head)
// write their tile TRANSPOSED into vt[h][d][s] instead of into C.
// ---------------------------------------------------------------------------
template <int WM, int WN, int FM, int FN, int BK, bool OUT_BF16, bool VT_SPLIT>
__global__ __launch_bounds__(WM * WN * 64) void gemm_kernel(
    const u16* __restrict__ A, const u16* __restrict__ BT,
    const float* __restrict__ bias, void* __restrict__ Cout,
    u16* __restrict__ vt, int M, int N, int K) {
  constexpr int BM = WM * FM * 16, BN = WN * FN * 16, T = WM * WN * 64;
  constexpr int RB = BK * 2;  // bytes per LDS row
  __shared__ u16 lds[2][(BM + BN) * BK];
  const int tid = threadIdx.x;
  const int lane = tid & 63, wave = tid >> 6;
  const int wr = wave / WN, wc = wave % WN;
  const int m0 = blockIdx.x * BM, n0 = blockIdx.y * BN;
  const int r = lane & 15, g = lane >> 4;
  const f32x4 fzero = {0.f, 0.f, 0.f, 0.f};
  f32x4 acc[FM][FN];
#pragma unroll
  for (int i = 0; i < FM; ++i)
#pragma unroll
    for (int j = 0; j < FN; ++j) acc[i][j] = fzero;

  constexpr int LA = (BM * RB) / (T * 16);
  constexpr int LB = (BN * RB) / (T * 16);

  auto stage = [&](int kt, int buf) {
    int k0 = kt * BK;
#pragma unroll
    for (int i = 0; i < LA; ++i) {
      int flat = i * T * 16 + tid * 16;
      int row = flat / RB, colb = flat % RB;
      async16((const char*)A + ((size_t)(m0 + row) * K + k0) * 2 + colb,
              (char*)lds[buf] + i * T * 16 + wave * 1024);
    }
#pragma unroll
    for (int i = 0; i < LB; ++i) {
      int flat = i * T * 16 + tid * 16;
      int row = flat / RB, colb = flat % RB;
      async16((const char*)BT + ((size_t)(n0 + row) * K + k0) * 2 + colb,
              (char*)lds[buf] + BM * RB + i * T * 16 + wave * 1024);
    }
  };

  stage(0, 0);
  asm volatile("s_waitcnt vmcnt(0)" ::: "memory");
  __syncthreads();

  const int NT = K / BK;
  for (int kt = 0; kt < NT; ++kt) {
    int cur = kt & 1;
    if (kt + 1 < NT) stage(kt + 1, cur ^ 1);
    const u16* Al = lds[cur];
    const u16* Bl = Al + BM * BK;
#pragma unroll
    for (int kk = 0; kk < BK / 32; ++kk) {
      bf16x8 af[FM], bfr[FN];
#pragma unroll
      for (int i = 0; i < FM; ++i)
        af[i] = *(const bf16x8*)&Al[(wr * FM * 16 + i * 16 + r) * BK + kk * 32 + g * 8];
#pragma unroll
      for (int j = 0; j < FN; ++j)
        bfr[j] = *(const bf16x8*)&Bl[(wc * FN * 16 + j * 16 + r) * BK + kk * 32 + g * 8];
#pragma unroll
      for (int i = 0; i < FM; ++i)
#pragma unroll
        for (int j = 0; j < FN; ++j)
          acc[i][j] = mfma16(af[i], bfr[j], acc[i][j]);
    }
    asm volatile("s_waitcnt vmcnt(0)" ::: "memory");
    __syncthreads();
  }

  if constexpr (VT_SPLIT) {
    if (n0 >= 2048) {  // V head: write transposed into vt[h][d][s]
      int h = (n0 - 2048) >> 6;
#pragma unroll
      for (int i = 0; i < FM; ++i)
#pragma unroll
        for (int j = 0; j < FN; ++j) {
          int d = wc * FN * 16 + j * 16 + r;        // 0..63
          int s0 = m0 + wr * FM * 16 + i * 16 + g * 4;
          float bval = bias[n0 + (d & 63)];
          ushort4 o = {f2bf(acc[i][j][0] + bval), f2bf(acc[i][j][1] + bval),
                       f2bf(acc[i][j][2] + bval), f2bf(acc[i][j][3] + bval)};
          *(ushort4*)(vt + (size_t)h * 131072 + (size_t)d * 2048 + s0) = o;
        }
      return;
    }
  }

#pragma unroll
  for (int i = 0; i < FM; ++i)
#pragma unroll
    for (int j = 0; j < FN; ++j)
#pragma unroll
      for (int e = 0; e < 4; ++e) {
        int row = m0 + wr * FM * 16 + i * 16 + g * 4 + e;
        int col = n0 + wc * FN * 16 + j * 16 + r;
        float v = acc[i][j][e] + bias[col];
        if constexpr (OUT_BF16)
          ((u16*)Cout)[(size_t)row * N + col] = f2bf(v);
        else
          ((float*)Cout)[(size_t)row * N + col] = v;
      }
}

// ---------------------------------------------------------------------------
// K4: flash attention, no-max softmax, swapped QK^T (S^T = K·Q^T).
// Block = (64 q-rows, head), 512 thr / 8 waves = 2 qg(32 rows) x 4 kv-split.
// Per step 128 keys staged (dbuf); wave kvw computes its 32 keys.
// P never touches LDS: cvt_pk pairs exchanged in-register via ds_bpermute
// (nt-register select AFTER the permute via lane&32 cndmask).
// 4 kv-partials merged once in LDS at the end.
// ---------------------------------------------------------------------------
__global__ __launch_bounds__(512) void attn_kernel(const u16* __restrict__ qkv,
                                                   const u16* __restrict__ vt,
                                                   u16* __restrict__ concat) {
  // LDS: K dbuf [2][128 keys][64 d] @0 (32KB), V dbuf [2][64 d][128 t] @32768 (32KB)
  // Epilogue aliases: Ox[3][64][65] f32 @0 (49920B), Lx[3][64] @49920.
  __shared__ __align__(16) char smem[65536];
  const int tid = threadIdx.x;
  const int lane = tid & 63, wave = tid >> 6;
  const int qg = wave >> 2, kvw = wave & 3;
  const int h = blockIdx.y;
  const int q0w = blockIdx.x * 64 + qg * 32;
  const int r = lane & 15, g = lane >> 4;
  const bool hi = (lane & 32) != 0;
  const int sa0 = (((lane & 16) << 1) | r) << 2;  // src lane 2*(g&1)*16 + r
  const int sa1 = sa0 + 64;                        // src lane +16
  const f32x4 fzero = {0.f, 0.f, 0.f, 0.f};

  bf16x8 aq[2][2];  // [qi][kk]: Q[q0w+qi*16+r][kk*32+g*8..] as B-fragment
#pragma unroll
  for (int qi = 0; qi < 2; ++qi)
#pragma unroll
    for (int kk = 0; kk < 2; ++kk)
      aq[qi][kk] = *(const bf16x8*)&qkv[(size_t)(q0w + qi * 16 + r) * 3072 +
                                        h * 64 + kk * 32 + g * 8];

  f32x4 acc[4][2];  // [d-tile][qi]
#pragma unroll
  for (int nt = 0; nt < 4; ++nt)
#pragma unroll
    for (int qi = 0; qi < 2; ++qi) acc[nt][qi] = fzero;
  float rs[2] = {0.f, 0.f};  // per-lane partial denom for q = qi*16 + r

  auto stage = [&](int step) {
    int par = step & 1;
    int t0 = step * 128;
#pragma unroll
    for (int i = 0; i < 2; ++i) {
      int flat = i * 8192 + tid * 16;
      int krow = flat >> 7;                       // 0..127
      int kslot = ((flat >> 4) & 7) ^ (krow & 7);
      async16((const char*)qkv +
                  ((size_t)(t0 + krow) * 3072 + 1024 + h * 64) * 2 + kslot * 16,
              smem + par * 16384 + flat);
      int vd = flat >> 8;                         // 0..63
      int vslot = ((flat >> 4) & 15) ^ (vd & 15);
      async16((const char*)vt +
                  ((size_t)h * 131072 + (size_t)vd * 2048 + t0 + vslot * 8) * 2,
              smem + 32768 + par * 16384 + flat);
    }
  };

  stage(0);
  asm volatile("s_waitcnt vmcnt(0)" ::: "memory");
  __syncthreads();

  for (int step = 0; step < 16; ++step) {
    if (step + 1 < 16) stage(step + 1);
    const int par = step & 1;
    const char* Kb = smem + par * 16384;
    const char* Vb = smem + 32768 + par * 16384;

    // S^T = K Q^T over this wave's 32 keys: sv[nt][qi][e] =
    //   S[q=qi*16+r][t = kvw*32 + nt*16 + g*4 + e]   (exp2 argument)
    f32x4 sv[2][2];
    __builtin_amdgcn_s_setprio(1);
#pragma unroll
    for (int nt = 0; nt < 2; ++nt) {
      sv[nt][0] = fzero;
      sv[nt][1] = fzero;
      int row = kvw * 32 + nt * 16 + r;
#pragma unroll
      for (int kk = 0; kk < 2; ++kk) {
        const bf16x8 bk = *(const bf16x8*)(Kb + row * 128 +
                                           ((((kk << 2) | g) ^ (row & 7)) << 4));
        sv[nt][0] = mfma16(bk, aq[0][kk], sv[nt][0]);
        sv[nt][1] = mfma16(bk, aq[1][kk], sv[nt][1]);
      }
    }
    __builtin_amdgcn_s_setprio(0);

    // p = exp2(s'); pack bf16 pairs in-register
    int w_[2][2][2];  // [nt][qi][pair]
#pragma unroll
    for (int nt = 0; nt < 2; ++nt)
#pragma unroll
      for (int qi = 0; qi < 2; ++qi) {
        float p0 = exp2f(sv[nt][qi][0]), p1 = exp2f(sv[nt][qi][1]);
        float p2 = exp2f(sv[nt][qi][2]), p3 = exp2f(sv[nt][qi][3]);
        rs[qi] += (p0 + p1) + (p2 + p3);
        w_[nt][qi][0] = (int)cvtpk_bf16(p0, p1);
        w_[nt][qi][1] = (int)cvtpk_bf16(p2, p3);
      }

    // PA fragment (A[m=q=r][k = g*8+j] over the wave's 32 keys) via bpermute:
    // pull both nt candidates from source lane, then select by dest nt=g>>1.
    bf16x8 pa[2];
#pragma unroll
    for (int qi = 0; qi < 2; ++qi) {
      int a0 = __builtin_amdgcn_ds_bpermute(sa0, w_[0][qi][0]);
      int a1 = __builtin_amdgcn_ds_bpermute(sa0, w_[1][qi][0]);
      int b0 = __builtin_amdgcn_ds_bpermute(sa0, w_[0][qi][1]);
      int b1 = __builtin_amdgcn_ds_bpermute(sa0, w_[1][qi][1]);
      int c0 = __builtin_amdgcn_ds_bpermute(sa1, w_[0][qi][0]);
      int c1 = __builtin_amdgcn_ds_bpermute(sa1, w_[1][qi][0]);
      int d0 = __builtin_amdgcn_ds_bpermute(sa1, w_[0][qi][1]);
      int d1 = __builtin_amdgcn_ds_bpermute(sa1, w_[1][qi][1]);
      int4 u = {hi ? a1 : a0, hi ? b1 : b0, hi ? c1 : c0, hi ? d1 : d0};
      pa[qi] = *(bf16x8*)&u;
    }

    // PV: O += P·V ; V B-frag from [d][t] LDS (16-slot XOR swizzle)
    __builtin_amdgcn_s_setprio(1);
#pragma unroll
    for (int nt = 0; nt < 4; ++nt) {
      int d = nt * 16 + r;
      const bf16x8 bv = *(const bf16x8*)(Vb + d * 256 +
                                         ((((kvw << 2) | g) ^ (d & 15)) << 4));
      acc[nt][0] = mfma16(pa[0], bv, acc[nt][0]);
      acc[nt][1] = mfma16(pa[1], bv, acc[nt][1]);
    }
    __builtin_amdgcn_s_setprio(0);
    asm volatile("s_waitcnt vmcnt(0)" ::: "memory");
    __syncthreads();
  }

  // full wave-local row-sums: reduce over the 4 g-groups
#pragma unroll
  for (int qi = 0; qi < 2; ++qi) {
    rs[qi] += __shfl_xor(rs[qi], 16, 64);
    rs[qi] += __shfl_xor(rs[qi], 32, 64);
  }

  // merge 4 kv-partials in LDS (aliases dead K/V buffers)
  float* Ox = (float*)smem;               // [3][64][65]
  float* Lx = (float*)(smem + 49920);     // [3][64]
  if (kvw != 0) {
    int kb = kvw - 1;
#pragma unroll
    for (int nt = 0; nt < 4; ++nt)
#pragma unroll
      for (int qi = 0; qi < 2; ++qi)
#pragma unroll
        for (int e = 0; e < 4; ++e) {
          int qb = qg * 32 + qi * 16 + (g << 2) + e;
          Ox[kb * 4160 + qb * 65 + nt * 16 + r] = acc[nt][qi][e];
        }
    if (g == 0) {
      Lx[kb * 64 + qg * 32 + r] = rs[0];
      Lx[kb * 64 + qg * 32 + 16 + r] = rs[1];
    }
  }
  __syncthreads();
  if (kvw == 0) {
#pragma unroll
    for (int qi = 0; qi < 2; ++qi) {
      float inv[4];
#pragma unroll
      for (int e = 0; e < 4; ++e) {
        int qb = qg * 32 + qi * 16 + (g << 2) + e;
        float own = __shfl(rs[qi], (g << 2) | e, 64);
        inv[e] = 1.f / (own + Lx[qb] + Lx[64 + qb] + Lx[128 + qb]);
      }
#pragma unroll
      for (int nt = 0; nt < 4; ++nt)
#pragma unroll
        for (int e = 0; e < 4; ++e) {
          int qb = qg * 32 + qi * 16 + (g << 2) + e;
          int d = nt * 16 + r;
          float o = acc[nt][qi][e] + Ox[qb * 65 + d] + Ox[4160 + qb * 65 + d] +
                    Ox[8320 + qb * 65 + d];
          concat[(size_t)(blockIdx.x * 64 + qb) * 1024 + h * 64 + d] =
              f2bf(o * inv[e]);
        }
    }
  }
}

// ---------------------------------------------------------------------------
extern "C" void kernel_launch(void* const* d_in, const int* in_sizes, int n_in,
                              void* d_out, int out_size, void* d_ws,
                              size_t ws_size, hipStream_t stream) {
  (void)in_sizes; (void)n_in; (void)out_size; (void)ws_size;
  const float* emb = (const float*)d_in[0];
  const float* Wq = (const float*)d_in[1];
  const float* bq = (const float*)d_in[2];
  const float* Wk = (const float*)d_in[3];
  const float* bk = (const float*)d_in[4];
  const float* Wv = (const float*)d_in[5];
  const float* bv = (const float*)d_in[6];
  const float* Wo = (const float*)d_in[7];
  const float* bo = (const float*)d_in[8];

  char* ws = (char*)d_ws;
  u16* emb_bf  = (u16*)(ws + 0);          // 4,194,304 B
  u16* wqkv_t  = (u16*)(ws + 4194304);    // 6,291,456 B
  u16* wo_t    = (u16*)(ws + 10485760);   // 2,097,152 B
  float* bqkv  = (float*)(ws + 12582912); // 12,288 B
  u16* qkv     = (u16*)(ws + 12595200);   // 12,582,912 B (V third unused)
  u16* vt      = (u16*)(ws + 25178112);   // 4,194,304 B
  u16* concat  = (u16*)(ws + 29372416);   // 4,194,304 B  (total ~33.6 MB)

  convert_kernel<<<3073, 256, 0, stream>>>(emb, Wq, Wk, Wv, bq, bk, bv, Wo,
                                           emb_bf, wqkv_t, wo_t, bqkv);
  gemm_kernel<2, 2, 4, 2, 64, true, true><<<dim3(16, 48), 256, 0, stream>>>(
      emb_bf, wqkv_t, bqkv, qkv, vt, 2048, 3072, 1024);
  attn_kernel<<<dim3(32, 16), 512, 0, stream>>>(qkv, vt, concat);
  gemm_kernel<2, 2, 2, 2, 64, false, false><<<dim3(32, 16), 256, 0, stream>>>(
      concat, wo_t, bo, d_out, nullptr, 2048, 1024, 1024);
}